// Round 3
// baseline (3370.339 us; speedup 1.0000x reference)
//
#include <hip/hip_runtime.h>
#include <hip/hip_fp16.h>

// Masked LSTM, T=512 B=64 D=512 H=512.
// Phase A: x_proj = inputs @ W_ih^T + (b_ih + b_hh), fp16 MFMA GEMM, fp16 out.
// Phase B: persistent recurrence, ONE WAVE PER BLOCK, zero LDS.
//   8 groups (8 batches each) x 32 blocks (16 h-dims each). Each wave holds its
//   64x512 W_hh slice as 256 VGPRs of MFMA B-frags (loaded once), computes all
//   4 gate tiles full-k (4 independent 16-deep MFMA chains), so i/f/g/o for a
//   given (batch,j) land in the SAME lane -> in-register epilogue, no LDS, no
//   __syncthreads data exchange. h read directly from LLC into A-frags (per-lane
//   address == fragment layout). Relaxed agent-scope (sc1) exchange + flag
//   barrier as before; out[] stores + next x_proj prefetch overlap the spin.

#define T_DIM 512
#define B_DIM 64
#define D_DIM 512
#define H_DIM 512
#define G_DIM 2048
#define M_DIM (T_DIM * B_DIM)

#define NGROUP 8
#define BPG 32
#define NBLK (NGROUP * BPG)     // 256

typedef __attribute__((ext_vector_type(8))) _Float16 half8;
typedef __attribute__((ext_vector_type(2))) __fp16 fp16x2;
typedef __attribute__((ext_vector_type(4))) float float4v;

#define AT_LD_U(p)    __hip_atomic_load((p), __ATOMIC_RELAXED, __HIP_MEMORY_SCOPE_AGENT)
#define AT_ST_U(p, v) __hip_atomic_store((p), (v), __ATOMIC_RELAXED, __HIP_MEMORY_SCOPE_AGENT)
#define AT_LD_I(p)    __hip_atomic_load((p), __ATOMIC_RELAXED, __HIP_MEMORY_SCOPE_AGENT)
#define AT_ST_I(p, v) __hip_atomic_store((p), (v), __ATOMIC_RELAXED, __HIP_MEMORY_SCOPE_AGENT)

__device__ __forceinline__ float sigf(float x) { return 1.0f / (1.0f + __expf(-x)); }
__device__ __forceinline__ float tanhfast(float x) { return 2.0f / (1.0f + __expf(-2.0f * x)) - 1.0f; }
__device__ __forceinline__ unsigned short f2h(float x) {
  return __builtin_bit_cast(unsigned short, (_Float16)x);
}
__device__ __forceinline__ unsigned pk2h(float a, float b) {
  fp16x2 h = __builtin_amdgcn_cvt_pkrtz(a, b);
  return __builtin_bit_cast(unsigned, h);
}

// ---------------------------------------------------------------- Phase A (fp16 MFMA)
__global__ __launch_bounds__(256) void xproj_mfma(
    const float* __restrict__ A, const float* __restrict__ W,
    const float* __restrict__ b1, const float* __restrict__ b2,
    __half* __restrict__ C) {
  __shared__ __align__(16) _Float16 As[128 * 72];
  __shared__ __align__(16) _Float16 Bs[128 * 72];
  const int tid = threadIdx.x;
  const int bid = blockIdx.x;
  const int xcd = bid & 7, idx = bid >> 3;
  const int mt = xcd * 32 + (idx >> 4);
  const int nt = idx & 15;
  const int lane = tid & 63;
  const int w = tid >> 6;
  const int wm = w >> 1, wn = w & 1;
  const int fr = lane & 15;
  const int ko = (lane >> 4) * 8;
  const int srow = tid >> 4, sf4 = tid & 15;

  const float* Ab = A + (size_t)(mt * 128) * D_DIM;
  const float* Wb = W + (size_t)(nt * 128) * D_DIM;

  float4v acc[4][4];
#pragma unroll
  for (int m = 0; m < 4; ++m)
#pragma unroll
    for (int n = 0; n < 4; ++n) acc[m][n] = (float4v){0.f, 0.f, 0.f, 0.f};

  for (int k0 = 0; k0 < D_DIM; k0 += 64) {
    float4 aR[8], wR[8];
#pragma unroll
    for (int i = 0; i < 8; ++i) {
      aR[i] = *(const float4*)(Ab + (size_t)(srow + i * 16) * D_DIM + k0 + sf4 * 4);
      wR[i] = *(const float4*)(Wb + (size_t)(srow + i * 16) * D_DIM + k0 + sf4 * 4);
    }
    __syncthreads();
#pragma unroll
    for (int i = 0; i < 8; ++i) {
      int row = srow + i * 16;
      *(uint2*)(As + row * 72 + sf4 * 4) =
          make_uint2(pk2h(aR[i].x, aR[i].y), pk2h(aR[i].z, aR[i].w));
      *(uint2*)(Bs + row * 72 + sf4 * 4) =
          make_uint2(pk2h(wR[i].x, wR[i].y), pk2h(wR[i].z, wR[i].w));
    }
    __syncthreads();
#pragma unroll
    for (int kk = 0; kk < 2; ++kk) {
      half8 af[4], bf[4];
#pragma unroll
      for (int m = 0; m < 4; ++m)
        af[m] = *(const half8*)(As + (wm * 64 + m * 16 + fr) * 72 + kk * 32 + ko);
#pragma unroll
      for (int n = 0; n < 4; ++n)
        bf[n] = *(const half8*)(Bs + (wn * 64 + n * 16 + fr) * 72 + kk * 32 + ko);
#pragma unroll
      for (int m = 0; m < 4; ++m)
#pragma unroll
        for (int n = 0; n < 4; ++n)
          acc[m][n] = __builtin_amdgcn_mfma_f32_16x16x32_f16(af[m], bf[n], acc[m][n], 0, 0, 0);
    }
  }
#pragma unroll
  for (int n = 0; n < 4; ++n) {
    int gcol = nt * 128 + wn * 64 + n * 16 + fr;
    float bias = b1[gcol] + b2[gcol];
#pragma unroll
    for (int m = 0; m < 4; ++m) {
      size_t grow = (size_t)(mt * 128 + wm * 64 + m * 16 + (lane >> 4) * 4);
      __half* cp = C + grow * G_DIM + gcol;
#pragma unroll
      for (int r = 0; r < 4; ++r)
        cp[(size_t)r * G_DIM] = (__half)(acc[m][n][r] + bias);
    }
  }
}

// ---------------------------------------------------------------- Phase B (1 wave/block)
__global__ __launch_bounds__(64, 1) void lstm_seq(
    const __half* __restrict__ xproj, const float* __restrict__ mask,
    const float* __restrict__ h0, const float* __restrict__ Whh,
    float* __restrict__ out, unsigned short* __restrict__ hbuf,
    int* slot_base) {
  const int tid = threadIdx.x;
  const int blk = blockIdx.x;
  const int grp = blk & 7;
  const int rank = blk >> 3;
  const int bbase = grp * 8;
  const int jbase = rank * 16;
  int* slots = (int*)((char*)slot_base + grp * 128);

  const int n = tid & 15;              // j within slice / fragment row
  const int koct = (tid >> 4) * 8;     // lane k-octet within 32-chunk
  const bool act = tid < 32;           // lanes holding real batches (m=0..7)
  const int g = (tid >> 4) & 1;
  const int jglob = jbase + n;

  // ---- W_hh slice -> 256 VGPRs of B-frags: w[q][kc] = row q*512+jbase+n, k koct
  half8 w[4][16];
#pragma unroll
  for (int q = 0; q < 4; ++q)
#pragma unroll
    for (int kc = 0; kc < 16; ++kc) {
      const float* wp = Whh + (size_t)(q * H_DIM + jbase + n) * H_DIM + kc * 32 + koct;
      float4 lo = *(const float4*)wp;
      float4 hi = *(const float4*)(wp + 4);
      uint4 u = make_uint4(pk2h(lo.x, lo.y), pk2h(lo.z, lo.w),
                           pk2h(hi.x, hi.y), pk2h(hi.z, hi.w));
      w[q][kc] = __builtin_bit_cast(half8, u);
    }

  int bglob[4];
  float h0v[4], cval[4];
#pragma unroll
  for (int r = 0; r < 4; ++r) {
    bglob[r] = bbase + 4 * g + r;
    h0v[r] = act ? h0[bglob[r] * H_DIM + jglob] : 0.f;
    cval[r] = h0v[r];
  }

  // ---- publish h0 into buffer 0 (pack fp16 pairs via shfl; even-n lanes store)
#pragma unroll
  for (int r = 0; r < 4; ++r) {
    int mybits = act ? (int)f2h(h0v[r]) : 0;
    int nb = __shfl_down(mybits, 1, 64);
    if (act && !(n & 1))
      AT_ST_U((unsigned*)hbuf + bglob[r] * 256 + (jglob >> 1),
              (unsigned)mybits | ((unsigned)nb << 16));
  }
  __syncthreads();   // drains vmcnt(0): publishes at coherence point (1-wave barrier)
  if (tid == 0) AT_ST_I(&slots[rank], 1);
  {
    int v;
    do {
      v = (tid < BPG) ? AT_LD_I(&slots[tid]) : 1;
      if (__all(v >= 1)) break;
      __builtin_amdgcn_s_sleep(2);
    } while (true);
  }
  __asm__ volatile("" ::: "memory");

  // ---- prefetch x_proj + mask for ts=0
  float xpv[16], mv[4];
  if (act) {
#pragma unroll
    for (int r = 0; r < 4; ++r) {
      mv[r] = mask[bglob[r]];
      const __half* xb = xproj + (size_t)bglob[r] * G_DIM + jglob;
#pragma unroll
      for (int q = 0; q < 4; ++q) xpv[q * 4 + r] = (float)xb[q * 512];
    }
  }

  const int arow = (bbase + (n & 7)) * 256;  // A-frag row base (uint index; dup for m>=8)

#pragma unroll 1
  for (int ts = 0; ts < T_DIM; ++ts) {
    const unsigned* cur32 = (const unsigned*)hbuf + (ts & 1) * (B_DIM * H_DIM / 2);
    unsigned* nxt32 = (unsigned*)hbuf + ((ts + 1) & 1) * (B_DIM * H_DIM / 2);

    // A-frags straight from LLC: lane reads h[batch n&7][kc*32+koct .. +8]
    uint4 ua[16];
#pragma unroll
    for (int kc = 0; kc < 16; ++kc) {
      unsigned* p = (unsigned*)&cur32[arow + (kc * 32 + koct) / 2];
      ua[kc].x = AT_LD_U(p);
      ua[kc].y = AT_LD_U(p + 1);
      ua[kc].z = AT_LD_U(p + 2);
      ua[kc].w = AT_LD_U(p + 3);
    }

    // 4 independent 16-deep MFMA chains (gates i,f,g,o), all in-register
    float4v ci = {0.f, 0.f, 0.f, 0.f}, cf = ci, cg = ci, co = ci;
#pragma unroll
    for (int kc = 0; kc < 16; ++kc) {
      half8 a = __builtin_bit_cast(half8, ua[kc]);
      ci = __builtin_amdgcn_mfma_f32_16x16x32_f16(a, w[0][kc], ci, 0, 0, 0);
      cf = __builtin_amdgcn_mfma_f32_16x16x32_f16(a, w[1][kc], cf, 0, 0, 0);
      cg = __builtin_amdgcn_mfma_f32_16x16x32_f16(a, w[2][kc], cg, 0, 0, 0);
      co = __builtin_amdgcn_mfma_f32_16x16x32_f16(a, w[3][kc], co, 0, 0, 0);
    }

    // in-lane epilogue: lane (g,n) reg r holds gates for (batch 4g+r, j=n)
    float hnew[4];
#pragma unroll
    for (int r = 0; r < 4; ++r) {
      float iv = sigf(ci[r] + xpv[r]);
      float fv = sigf(cf[r] + xpv[4 + r]);
      float gv = tanhfast(cg[r] + xpv[8 + r]);
      float ov = sigf(co[r] + xpv[12 + r]);
      float cn = fv * cval[r] + iv * gv;
      float hn = ov * tanhfast(cn);
      hn = hn * mv[r] + h0v[r] * (1.f - mv[r]);
      cn = cn * mv[r] + h0v[r] * (1.f - mv[r]);
      cval[r] = cn;
      hnew[r] = hn;
    }

    // publish h_new (packed pairs, sc1)
#pragma unroll
    for (int r = 0; r < 4; ++r) {
      int mybits = act ? (int)f2h(hnew[r]) : 0;
      int nb = __shfl_down(mybits, 1, 64);
      if (act && !(n & 1))
        AT_ST_U(nxt32 + bglob[r] * 256 + (jglob >> 1),
                (unsigned)mybits | ((unsigned)nb << 16));
    }
    __syncthreads();   // vmcnt(0) drain -> publishes visible before flag
    if (tid == 0) AT_ST_I(&slots[rank], ts + 2);

    // out stores + next-step prefetch overlap the spin
    if (act) {
#pragma unroll
      for (int r = 0; r < 4; ++r)
        out[((size_t)ts * B_DIM + bglob[r]) * H_DIM + jglob] = hnew[r];
      if (ts == T_DIM - 1) {
#pragma unroll
        for (int r = 0; r < 4; ++r) {
          out[(size_t)T_DIM * B_DIM * H_DIM + bglob[r] * H_DIM + jglob] = hnew[r];
          out[(size_t)T_DIM * B_DIM * H_DIM + B_DIM * H_DIM + bglob[r] * H_DIM + jglob] = cval[r];
        }
      }
      if (ts + 1 < T_DIM) {
#pragma unroll
        for (int r = 0; r < 4; ++r) {
          mv[r] = mask[(ts + 1) * B_DIM + bglob[r]];
          const __half* xb = xproj + ((size_t)(ts + 1) * B_DIM + bglob[r]) * G_DIM + jglob;
#pragma unroll
          for (int q = 0; q < 4; ++q) xpv[q * 4 + r] = (float)xb[q * 512];
        }
      }
    }

    {
      int v;
      do {
        v = (tid < BPG) ? AT_LD_I(&slots[tid]) : (ts + 2);
        if (__all(v >= ts + 2)) break;
        __builtin_amdgcn_s_sleep(2);
      } while (true);
    }
    __asm__ volatile("" ::: "memory");
  }
}

// ---------------------------------------------------------------- launch
extern "C" void kernel_launch(void* const* d_in, const int* in_sizes, int n_in,
                              void* d_out, int out_size, void* d_ws, size_t ws_size,
                              hipStream_t stream) {
  const float* inputs = (const float*)d_in[0];
  const float* maskp  = (const float*)d_in[1];
  const float* h0     = (const float*)d_in[2];
  const float* W_ih   = (const float*)d_in[3];
  const float* W_hh   = (const float*)d_in[4];
  const float* b_ih   = (const float*)d_in[5];
  const float* b_hh   = (const float*)d_in[6];
  float* out = (float*)d_out;

  char* ws = (char*)d_ws;
  int* slot_base = (int*)ws;                            // 8 groups x 32 slots (128B apart)
  unsigned short* hbuf = (unsigned short*)(ws + 4096);  // fp16 h double buffer, 128KB
  __half* xp = (__half*)(ws + 4096 + 2 * (size_t)B_DIM * H_DIM * sizeof(unsigned short));

  (void)hipMemsetAsync(d_ws, 0, 4096, stream);

  xproj_mfma<<<dim3((M_DIM / 128) * (G_DIM / 128)), 256, 0, stream>>>(
      inputs, W_ih, b_ih, b_hh, xp);
  lstm_seq<<<NBLK, 64, 0, stream>>>(xp, maskp, h0, W_hh, out, hbuf, slot_base);

  (void)in_sizes; (void)n_in; (void)out_size; (void)ws_size;
}